// Round 7
// baseline (151.556 us; speedup 1.0000x reference)
//
#include <hip/hip_runtime.h>
#include <hip/hip_bf16.h>

typedef __attribute__((ext_vector_type(8))) short short8_t;
typedef __attribute__((ext_vector_type(4))) short s4v;
typedef __attribute__((ext_vector_type(4))) float f32x4_t;
using u16 = unsigned short;

constexpr int S_LEN = 2048;
constexpr int EMB   = 1024;
constexpr int NH    = 16;
constexpr int HD    = 64;
constexpr int BATCH = 2;
constexpr int MR    = BATCH * S_LEN;  // 4096
constexpr int E3    = 3 * EMB;        // 3072

#define L2E 1.44269504f

__device__ __forceinline__ u16 f2bf(float f) {
  unsigned u = __builtin_bit_cast(unsigned, f);
  unsigned r = 0x7fffu + ((u >> 16) & 1u);
  return (u16)((u + r) >> 16);
}

__device__ __forceinline__ void gld16(const void* g, void* l) {
  __builtin_amdgcn_global_load_lds(
      (const __attribute__((address_space(1))) void*)g,
      (__attribute__((address_space(3))) void*)l, 16, 0, 0);
}

// hardware transpose read. Canonical per-lane address = base + 8B*lane:
// lane l, elem j <- lds_elem[64*(l>>4) + 16*j + (l&15)] (+ offset/2 elems).
template <int OFF>
__device__ __forceinline__ s4v tr16(const __attribute__((address_space(3))) u16* p) {
  s4v d;
  asm volatile("ds_read_b64_tr_b16 %0, %1 offset:%2"
               : "=v"(d) : "v"(p), "n"(OFF));
  return d;
}

// ---------------- fused fp32 -> bf16 conversion ----------------------------
// dest layout (contiguous in ws): xb(4M) | Wq(1M,*0.125) | Wk | Wv | Wo
__global__ void k_cvt_all(const float* __restrict__ x, const float* __restrict__ Wq,
                          const float* __restrict__ Wk, const float* __restrict__ Wv,
                          const float* __restrict__ Wo, u16* __restrict__ out) {
  int i = blockIdx.x * 256 + threadIdx.x;  // float4 index, total 2M
  const float* src;
  int j;
  float sc = 1.0f;
  if (i < (1 << 20)) {
    src = x; j = i;
  } else {
    int jj = i - (1 << 20);
    int r = jj >> 18;
    j = jj & ((1 << 18) - 1);
    src = (r == 0) ? Wq : (r == 1) ? Wk : (r == 2) ? Wv : Wo;
    if (r == 0) sc = 0.125f;  // fold softmax 1/sqrt(64)
  }
  float4 v = reinterpret_cast<const float4*>(src)[j];
  ushort4 o;
  o.x = f2bf(v.x * sc); o.y = f2bf(v.y * sc);
  o.z = f2bf(v.z * sc); o.w = f2bf(v.w * sc);
  reinterpret_cast<ushort4*>(out)[i] = o;
}

// ---------------- bf16 GEMM, B^T input (C = A @ B^T), 128x128 tile ---------
template <bool F32OUT>
__global__ __launch_bounds__(256) void k_gemm_bt(
    const u16* __restrict__ A, const u16* __restrict__ Bw,
    void* __restrict__ Cv, const float* __restrict__ bias,
    int M, int N, int K) {
  __shared__ short As[128 * 32];
  __shared__ short Bs[128 * 32];
  const int t    = threadIdx.x;
  const int w    = t >> 6;
  const int ln15 = t & 15;
  const int lg   = (t >> 4) & 3;
  const int wr   = w >> 1, wc = w & 1;
  const int m0   = blockIdx.y * 128, n0 = blockIdx.x * 128;

  const int srow = t >> 2;
  const int scol = (t & 3) * 8;
  const u16* gA = A + (size_t)(m0 + srow) * K + scol;
  const u16* gB = Bw + (size_t)(n0 + srow) * K + scol;
  short* lA = As + w * 512;
  short* lB = Bs + w * 512;

  f32x4_t acc[4][4] = {};

  for (int k0 = 0; k0 < K; k0 += 32) {
    gld16(gA + k0, lA);
    gld16(gA + (size_t)64 * K + k0, lA + 2048);
    gld16(gB + k0, lB);
    gld16(gB + (size_t)64 * K + k0, lB + 2048);
    __syncthreads();
    short8_t af[4], bf[4];
#pragma unroll
    for (int i = 0; i < 4; ++i) {
      af[i] = *reinterpret_cast<const short8_t*>(
          &As[(wr * 64 + i * 16 + ln15) * 32 + 8 * lg]);
      bf[i] = *reinterpret_cast<const short8_t*>(
          &Bs[(wc * 64 + i * 16 + ln15) * 32 + 8 * lg]);
    }
#pragma unroll
    for (int i = 0; i < 4; ++i)
#pragma unroll
      for (int j = 0; j < 4; ++j)
        acc[i][j] = __builtin_amdgcn_mfma_f32_16x16x32_bf16(
            af[i], bf[j], acc[i][j], 0, 0, 0);
    __syncthreads();
  }

  if (F32OUT) {
    float* C = reinterpret_cast<float*>(Cv);
#pragma unroll
    for (int i = 0; i < 4; ++i)
#pragma unroll
      for (int j = 0; j < 4; ++j) {
        const int col = n0 + wc * 64 + j * 16 + ln15;
        const float bv = bias ? bias[col] : 0.0f;
#pragma unroll
        for (int r = 0; r < 4; ++r) {
          const int row = m0 + wr * 64 + i * 16 + lg * 4 + r;
          C[(size_t)row * N + col] = acc[i][j][r] + bv;
        }
      }
  } else {
    u16* C = reinterpret_cast<u16*>(Cv);
#pragma unroll
    for (int i = 0; i < 4; ++i)
#pragma unroll
      for (int j = 0; j < 4; ++j) {
        const int col = n0 + wc * 64 + j * 16 + ln15;
#pragma unroll
        for (int r = 0; r < 4; ++r) {
          const int row = m0 + wr * 64 + i * 16 + lg * 4 + r;
          C[(size_t)row * N + col] = f2bf(acc[i][j][r]);
        }
      }
  }
}

// ---------------- causal flash attention, swapped-QK^T ----------------------
// QKV: (MR,3072) bf16: [0,1024)=Q (pre-scaled 1/8), [1024,2048)=K, [2048,3072)=V
// grid: (32 bh, 32 y->qt, LPT). 2 waves/block of 128 threads; each wave owns
// 32 q-rows as 2 subtiles of 16; KV tiles of 64. K/V tiles + all fragment
// layouts identical to the r3-verified ones; per-tile fixed costs (staging,
// barriers, K-frag reads, V tr-reads) amortized over 2x the scores.
// K in LDS: [64][64] chunk-swizzled (col8 ^= row&7, pre-swizzled src).
// V in LDS: [dc=4][kv=64][dl=16], read via tr16.
__global__ __launch_bounds__(128, 2) void k_attn2(const u16* __restrict__ QKV,
                                                  u16* __restrict__ ctx) {
  __shared__ u16 Ks[2][64 * 64];
  __shared__ u16 Vs[2][64 * 64];

  const int t    = threadIdx.x;
  const int w    = t >> 6;          // 0..1
  const int l    = t & 63;
  const int ln15 = t & 15;
  const int lg   = (l >> 4) & 3;

  // LPT: heaviest qt dispatched first
  const int qt = 31 - blockIdx.y;
  const int bh = blockIdx.x;
  const int b  = bh >> 4, h = bh & 15;

  const u16* KVb = QKV + (size_t)b * S_LEN * E3 + h * HD;
  const u16* Kg  = KVb + 1024;
  const u16* Vg  = KVb + 2048;
  const int qrow_w = qt * 64 + w * 32;   // wave's 32 q-rows

  // Q fragments (B-operand), 2 subtiles: Q[qrow_w+16*sub+ln15][32*kh+8*lg..+7]
  short8_t qf[2][2];
#pragma unroll
  for (int sub = 0; sub < 2; ++sub) {
    const u16* qp = KVb + (size_t)(qrow_w + 16 * sub + ln15) * E3 + 8 * lg;
    qf[sub][0] = *reinterpret_cast<const short8_t*>(qp);
    qf[sub][1] = *reinterpret_cast<const short8_t*>(qp + 32);
  }

  // staging addresses (w,i-invariant swizzle):
  // K: round i=0..3: row = 32w + 8i + (l>>3), src col = 8*((l&7)^(l>>3)),
  //    lds = w*2048 + i*512 + 8l  (chunk at pos l&7 holds logical (l&7)^(row&7))
  // V: round j=4w+i: src = V[kv0 + 32*(j&1) + (l>>1)][16*(j>>1) + 8*(l&1)],
  //    lds = j*512 + 8l  -> [dc=j>>1][kv=32*(j&1)+(l>>1)][dl=8*(l&1)]
  const int krlo  = l >> 3;
  const int kcsrc = 8 * ((l & 7) ^ krlo);
  const int vkv   = l >> 1;
  const int vdl   = 8 * (l & 1);

  // K-frag read offsets (swizzled): position = logical-chunk ^ (row&7)
  const int kx  = 8 * (ln15 & 7);
  const int kc0 = (8 * lg) ^ kx;
  const int kc1 = (32 + 8 * lg) ^ kx;

#define STAGE(buf, kv0)                                                        \
  do {                                                                         \
    _Pragma("unroll")                                                          \
    for (int i = 0; i < 4; ++i)                                                \
      gld16(Kg + (size_t)((kv0) + 32 * w + 8 * i + krlo) * E3 + kcsrc,         \
            &Ks[buf][w * 2048 + i * 512]);                                     \
    _Pragma("unroll")                                                          \
    for (int i = 0; i < 4; ++i) {                                              \
      const int j = 4 * w + i;                                                 \
      gld16(Vg + (size_t)((kv0) + 32 * (j & 1) + vkv) * E3 + 16 * (j >> 1) + vdl, \
            &Vs[buf][j * 512]);                                                \
    }                                                                          \
  } while (0)

  f32x4_t o[2][4] = {};
  float mrow[2] = {-3e38f, -3e38f}, lrow[2] = {0.0f, 0.0f};
  const int nt_tiles = qt + 1;

  STAGE(0, 0);
  int cur = 0;

  for (int kvt = 0; kvt < nt_tiles; ++kvt) {
    const int kv0 = kvt * 64;
    asm volatile("s_barrier" ::: "memory");  // all waves done reading buf[cur^1]
    if (kvt + 1 < nt_tiles) {
      STAGE(cur ^ 1, kv0 + 64);
      asm volatile("s_waitcnt vmcnt(8)" ::: "memory");  // this tile's 8 landed
    } else {
      asm volatile("s_waitcnt vmcnt(0)" ::: "memory");
    }
    asm volatile("s_barrier" ::: "memory");  // buf[cur] ready for all waves

    // ---- S^T = mfma(K, Q): lane holds S[q][kv=kv0+16ks+4lg+r], q per sub ----
    f32x4_t tacc[2][4];
    __builtin_amdgcn_s_setprio(1);
#pragma unroll
    for (int ks = 0; ks < 4; ++ks) {
      const int R = 16 * ks + ln15;
      short8_t kf0 = *reinterpret_cast<const short8_t*>(&Ks[cur][R * 64 + kc0]);
      short8_t kf1 = *reinterpret_cast<const short8_t*>(&Ks[cur][R * 64 + kc1]);
#pragma unroll
      for (int sub = 0; sub < 2; ++sub) {
        f32x4_t a = {0.f, 0.f, 0.f, 0.f};
        a = __builtin_amdgcn_mfma_f32_16x16x32_bf16(kf0, qf[sub][0], a, 0, 0, 0);
        a = __builtin_amdgcn_mfma_f32_16x16x32_bf16(kf1, qf[sub][1], a, 0, 0, 0);
        tacc[sub][ks] = a;
      }
    }
    __builtin_amdgcn_s_setprio(0);

    // ---- V tr-reads issued after QK (hide under softmax; in-order lgkmcnt
    // would otherwise delay the K-frag waits) ----
    const __attribute__((address_space(3))) u16* vp =
        (const __attribute__((address_space(3))) u16*)&Vs[cur][4 * l];
    s4v vf[4][2][2];
#pragma unroll
    for (int nt = 0; nt < 4; ++nt) {
      if (nt == 0) { vf[0][0][0]=tr16<0>(vp);    vf[0][0][1]=tr16<512>(vp);
                     vf[0][1][0]=tr16<1024>(vp); vf[0][1][1]=tr16<1536>(vp); }
      if (nt == 1) { vf[1][0][0]=tr16<2048>(vp); vf[1][0][1]=tr16<2560>(vp);
                     vf[1][1][0]=tr16<3072>(vp); vf[1][1][1]=tr16<3584>(vp); }
      if (nt == 2) { vf[2][0][0]=tr16<4096>(vp); vf[2][0][1]=tr16<4608>(vp);
                     vf[2][1][0]=tr16<5120>(vp); vf[2][1][1]=tr16<5632>(vp); }
      if (nt == 3) { vf[3][0][0]=tr16<6144>(vp); vf[3][0][1]=tr16<6656>(vp);
                     vf[3][1][0]=tr16<7168>(vp); vf[3][1][1]=tr16<7680>(vp); }
    }

    // ---- causal mask (diagonal tile only) ----
    if (kvt == qt) {
#pragma unroll
      for (int sub = 0; sub < 2; ++sub) {
        const int qg = qrow_w + 16 * sub + ln15;
#pragma unroll
        for (int ks = 0; ks < 4; ++ks)
#pragma unroll
          for (int r = 0; r < 4; ++r)
            if (kv0 + 16 * ks + 4 * lg + r > qg) tacc[sub][ks][r] = -3e38f;
      }
    }

    // ---- online softmax per sub (lane owns 16 of row q's values) ----
    float rm[2];
#pragma unroll
    for (int sub = 0; sub < 2; ++sub) {
      float m = fmaxf(
          fmaxf(fmaxf(fmaxf(tacc[sub][0][0], tacc[sub][0][1]), fmaxf(tacc[sub][0][2], tacc[sub][0][3])),
                fmaxf(fmaxf(tacc[sub][1][0], tacc[sub][1][1]), fmaxf(tacc[sub][1][2], tacc[sub][1][3]))),
          fmaxf(fmaxf(fmaxf(tacc[sub][2][0], tacc[sub][2][1]), fmaxf(tacc[sub][2][2], tacc[sub][2][3])),
                fmaxf(fmaxf(tacc[sub][3][0], tacc[sub][3][1]), fmaxf(tacc[sub][3][2], tacc[sub][3][3]))));
      m = fmaxf(m, __shfl_xor(m, 16, 64));
      m = fmaxf(m, __shfl_xor(m, 32, 64));
      rm[sub] = m;
    }

    // THR=0 exact-skip (skipped rescale would multiply by exactly 1.0)
    if (__any(fmaxf(rm[0] - mrow[0], rm[1] - mrow[1]) > 0.0f)) {
#pragma unroll
      for (int sub = 0; sub < 2; ++sub) {
        const float nm = fmaxf(mrow[sub], rm[sub]);
        const float sc = exp2f((mrow[sub] - nm) * L2E);
        mrow[sub] = nm;
        lrow[sub] *= sc;
#pragma unroll
        for (int r = 0; r < 4; ++r) {
          const float so = __shfl(sc, 20 * lg + r, 64);
#pragma unroll
          for (int nt = 0; nt < 4; ++nt) o[sub][nt][r] *= so;
        }
      }
    }

    float p[2][4][4];
#pragma unroll
    for (int sub = 0; sub < 2; ++sub) {
      const float nmL = mrow[sub] * L2E;
      float rs = 0.0f;
#pragma unroll
      for (int ks = 0; ks < 4; ++ks)
#pragma unroll
        for (int r = 0; r < 4; ++r) {
          const float pv = exp2f(fmaf(tacc[sub][ks][r], L2E, -nmL));
          p[sub][ks][r] = pv;
          rs += pv;
        }
      rs += __shfl_xor(rs, 16, 64);
      rs += __shfl_xor(rs, 32, 64);
      lrow[sub] += rs;
    }

    // ---- P pack (r3/r5-verified bit-hack path) ----
    short8_t pf[2][2];
#pragma unroll
    for (int sub = 0; sub < 2; ++sub)
#pragma unroll
      for (int s2 = 0; s2 < 2; ++s2)
#pragma unroll
        for (int j = 0; j < 4; ++j) {
          pf[sub][s2][j]     = (short)f2bf(p[sub][2 * s2][j]);
          pf[sub][s2][j + 4] = (short)f2bf(p[sub][2 * s2 + 1][j]);
        }

    asm volatile("s_waitcnt lgkmcnt(0)");
    __builtin_amdgcn_sched_barrier(0);

    __builtin_amdgcn_s_setprio(1);
#pragma unroll
    for (int nt = 0; nt < 4; ++nt) {
#pragma unroll
      for (int s2 = 0; s2 < 2; ++s2) {
        short8_t bv = __builtin_shufflevector(vf[nt][s2][0], vf[nt][s2][1],
                                              0, 1, 2, 3, 4, 5, 6, 7);
        o[0][nt] = __builtin_amdgcn_mfma_f32_16x16x32_bf16(pf[0][s2], bv, o[0][nt], 0, 0, 0);
        o[1][nt] = __builtin_amdgcn_mfma_f32_16x16x32_bf16(pf[1][s2], bv, o[1][nt], 0, 0, 0);
      }
    }
    __builtin_amdgcn_s_setprio(0);
    cur ^= 1;
  }
#undef STAGE

  // ---- epilogue: normalize and write ctx ----
#pragma unroll
  for (int sub = 0; sub < 2; ++sub) {
    const float linv = 1.0f / lrow[sub];
#pragma unroll
    for (int r = 0; r < 4; ++r) {
      const float li = __shfl(linv, 20 * lg + r, 64);
      u16* op = ctx + (size_t)(b * S_LEN + qrow_w + 16 * sub + 4 * lg + r) * EMB + h * HD;
#pragma unroll
      for (int nt = 0; nt < 4; ++nt)
        op[nt * 16 + ln15] = f2bf(o[sub][nt][r] * li);
    }
  }
}

// ---------------------------------------------------------------------------
extern "C" void kernel_launch(void* const* d_in, const int* in_sizes, int n_in,
                              void* d_out, int out_size, void* d_ws, size_t ws_size,
                              hipStream_t stream) {
  const float* x  = (const float*)d_in[0];
  const float* Wq = (const float*)d_in[1];
  const float* Wk = (const float*)d_in[2];
  const float* Wv = (const float*)d_in[3];
  const float* Wo = (const float*)d_in[4];
  const float* bo = (const float*)d_in[5];

  u16* ws   = (u16*)d_ws;
  u16* xb   = ws;                               // 4096*1024
  u16* wcat = xb + (size_t)MR * EMB;            // 3*1024*1024 (Wq|Wk|Wv rows)
  u16* wob  = wcat + (size_t)3 * EMB * EMB;     // 1024*1024
  u16* qkv  = wob + (size_t)EMB * EMB;          // 4096*3072
  u16* ctxb = qkv + (size_t)MR * E3;            // 4096*1024

  // fused fp32 -> bf16 (x | Wq*0.125 | Wk | Wv | Wo), dest contiguous at xb
  k_cvt_all<<<8192, 256, 0, stream>>>(x, Wq, Wk, Wv, Wo, xb);

  // QKV = x @ Wcat^T  (M=4096, N=3072, K=1024), bf16 out
  k_gemm_bt<false><<<dim3(E3 / 128, MR / 128), 256, 0, stream>>>(
      xb, wcat, qkv, nullptr, MR, E3, EMB);

  // causal flash attention -> ctx (bf16)
  k_attn2<<<dim3(BATCH * NH, 32), 128, 0, stream>>>(qkv, ctxb);

  // out = ctx @ Wo^T + bo  (fp32 out)
  k_gemm_bt<true><<<dim3(EMB / 128, MR / 128), 256, 0, stream>>>(
      ctxb, wob, d_out, bo, MR, EMB, EMB);
}

// Round 8
// 124.097 us; speedup vs baseline: 1.2213x; 1.2213x over previous
//
#include <hip/hip_runtime.h>
#include <hip/hip_bf16.h>

typedef __attribute__((ext_vector_type(8))) short short8_t;
typedef __attribute__((ext_vector_type(4))) short s4v;
typedef __attribute__((ext_vector_type(4))) float f32x4_t;
typedef __attribute__((ext_vector_type(4))) unsigned u32x4_t;
using u16 = unsigned short;

constexpr int S_LEN = 2048;
constexpr int EMB   = 1024;
constexpr int NH    = 16;
constexpr int HD    = 64;
constexpr int BATCH = 2;
constexpr int MR    = BATCH * S_LEN;  // 4096
constexpr int E3    = 3 * EMB;        // 3072

#define L2E 1.44269504f

__device__ __forceinline__ u16 f2bf(float f) {
  unsigned u = __builtin_bit_cast(unsigned, f);
  unsigned r = 0x7fffu + ((u >> 16) & 1u);
  return (u16)((u + r) >> 16);
}

// packed f32x2 -> bf16x2 via intrinsic (RNE, compiler emits v_cvt_pk_bf16_f32)
__device__ __forceinline__ unsigned pkbf(float a, float b) {
  __hip_bfloat162 h = __float22bfloat162_rn(make_float2(a, b));
  unsigned u;
  __builtin_memcpy(&u, &h, 4);
  return u;
}

__device__ __forceinline__ void gld16(const void* g, void* l) {
  __builtin_amdgcn_global_load_lds(
      (const __attribute__((address_space(1))) void*)g,
      (__attribute__((address_space(3))) void*)l, 16, 0, 0);
}

// hardware transpose read. Canonical per-lane address = base + 8B*lane:
// lane l, elem j <- lds_elem[64*(l>>4) + 16*j + (l&15)] (+ offset/2 elems).
template <int OFF>
__device__ __forceinline__ s4v tr16(const __attribute__((address_space(3))) u16* p) {
  s4v d;
  asm volatile("ds_read_b64_tr_b16 %0, %1 offset:%2"
               : "=v"(d) : "v"(p), "n"(OFF));
  return d;
}

// ---------------- fused fp32 -> bf16 conversion ----------------------------
// dest layout (contiguous in ws): xb(4M) | Wq(1M,*0.125) | Wk | Wv | Wo
__global__ void k_cvt_all(const float* __restrict__ x, const float* __restrict__ Wq,
                          const float* __restrict__ Wk, const float* __restrict__ Wv,
                          const float* __restrict__ Wo, u16* __restrict__ out) {
  int i = blockIdx.x * 256 + threadIdx.x;  // float4 index, total 2M
  const float* src;
  int j;
  float sc = 1.0f;
  if (i < (1 << 20)) {
    src = x; j = i;
  } else {
    int jj = i - (1 << 20);
    int r = jj >> 18;
    j = jj & ((1 << 18) - 1);
    src = (r == 0) ? Wq : (r == 1) ? Wk : (r == 2) ? Wv : Wo;
    if (r == 0) sc = 0.125f;  // fold softmax 1/sqrt(64)
  }
  float4 v = reinterpret_cast<const float4*>(src)[j];
  ushort4 o;
  o.x = f2bf(v.x * sc); o.y = f2bf(v.y * sc);
  o.z = f2bf(v.z * sc); o.w = f2bf(v.w * sc);
  reinterpret_cast<ushort4*>(out)[i] = o;
}

// ---------------- bf16 GEMM, B^T input (C = A @ B^T), 128x128 tile ---------
// T1 XCD swizzle: grids are multiples of 8 blocks (768, 256) -> bijective.
template <bool F32OUT>
__global__ __launch_bounds__(256) void k_gemm_bt(
    const u16* __restrict__ A, const u16* __restrict__ Bw,
    void* __restrict__ Cv, const float* __restrict__ bias,
    int M, int N, int K) {
  __shared__ short As[128 * 32];
  __shared__ short Bs[128 * 32];
  const int t    = threadIdx.x;
  const int w    = t >> 6;
  const int ln15 = t & 15;
  const int lg   = (t >> 4) & 3;
  const int wr   = w >> 1, wc = w & 1;

  // XCD-aware block remap (nwg % 8 == 0 for all launches here)
  const int nwgx = gridDim.x;
  const int lin  = blockIdx.y * nwgx + blockIdx.x;
  const int cpx  = (nwgx * gridDim.y) >> 3;
  const int lin2 = (lin & 7) * cpx + (lin >> 3);
  const int m0   = (lin2 / nwgx) * 128;
  const int n0   = (lin2 % nwgx) * 128;

  const int srow = t >> 2;
  const int scol = (t & 3) * 8;
  const u16* gA = A + (size_t)(m0 + srow) * K + scol;
  const u16* gB = Bw + (size_t)(n0 + srow) * K + scol;
  short* lA = As + w * 512;
  short* lB = Bs + w * 512;

  f32x4_t acc[4][4] = {};

  for (int k0 = 0; k0 < K; k0 += 32) {
    gld16(gA + k0, lA);
    gld16(gA + (size_t)64 * K + k0, lA + 2048);
    gld16(gB + k0, lB);
    gld16(gB + (size_t)64 * K + k0, lB + 2048);
    __syncthreads();
    short8_t af[4], bf[4];
#pragma unroll
    for (int i = 0; i < 4; ++i) {
      af[i] = *reinterpret_cast<const short8_t*>(
          &As[(wr * 64 + i * 16 + ln15) * 32 + 8 * lg]);
      bf[i] = *reinterpret_cast<const short8_t*>(
          &Bs[(wc * 64 + i * 16 + ln15) * 32 + 8 * lg]);
    }
#pragma unroll
    for (int i = 0; i < 4; ++i)
#pragma unroll
      for (int j = 0; j < 4; ++j)
        acc[i][j] = __builtin_amdgcn_mfma_f32_16x16x32_bf16(
            af[i], bf[j], acc[i][j], 0, 0, 0);
    __syncthreads();
  }

  if (F32OUT) {
    float* C = reinterpret_cast<float*>(Cv);
#pragma unroll
    for (int i = 0; i < 4; ++i)
#pragma unroll
      for (int j = 0; j < 4; ++j) {
        const int col = n0 + wc * 64 + j * 16 + ln15;
        const float bv = bias ? bias[col] : 0.0f;
#pragma unroll
        for (int r = 0; r < 4; ++r) {
          const int row = m0 + wr * 64 + i * 16 + lg * 4 + r;
          C[(size_t)row * N + col] = acc[i][j][r] + bv;
        }
      }
  } else {
    u16* C = reinterpret_cast<u16*>(Cv);
#pragma unroll
    for (int i = 0; i < 4; ++i)
#pragma unroll
      for (int j = 0; j < 4; ++j) {
        const int col = n0 + wc * 64 + j * 16 + ln15;
#pragma unroll
        for (int r = 0; r < 4; ++r) {
          const int row = m0 + wr * 64 + i * 16 + lg * 4 + r;
          C[(size_t)row * N + col] = f2bf(acc[i][j][r]);
        }
      }
  }
}

// ---------------- causal flash attention, swapped-QK^T ----------------------
// r5-verified structure (54 us): 4 waves/block, 16 q-rows/wave, KV tiles 64.
// Only change: P-pack via v_cvt_pk_bf16_f32 (8 ops vs 48 bit-hack ops).
__global__ __launch_bounds__(256, 4) void k_attn2(const u16* __restrict__ QKV,
                                                  u16* __restrict__ ctx) {
  __shared__ u16 Ks[2][64 * 64];
  __shared__ u16 Vs[2][64 * 64];

  const int t    = threadIdx.x;
  const int w    = t >> 6;
  const int l    = t & 63;
  const int ln15 = t & 15;
  const int lg   = (l >> 4) & 3;

  // LPT: heaviest qt dispatched first
  const int qt = 31 - blockIdx.y;
  const int bh = blockIdx.x;
  const int b  = bh >> 4, h = bh & 15;

  const u16* KVb = QKV + (size_t)b * S_LEN * E3 + h * HD;
  const u16* Kg  = KVb + 1024;
  const u16* Vg  = KVb + 2048;
  const int qrow = qt * 64 + w * 16;

  // Q fragments (B-operand): lane (ln15,lg): Q[qrow+ln15][32*sd + 8*lg ..+7]
  short8_t qf[2];
  {
    const u16* qp = KVb + (size_t)(qrow + ln15) * E3 + 8 * lg;
    qf[0] = *reinterpret_cast<const short8_t*>(qp);
    qf[1] = *reinterpret_cast<const short8_t*>(qp + 32);
  }

  // staging address components
  const int krow_lo = l >> 3;                    // row&7 of K stage row
  const int kcol    = 8 * ((l & 7) ^ krow_lo);   // pre-swizzled source col
  const int vkv     = l >> 1;                    // 0..31
  const int vcol    = 16 * w + 8 * (l & 1);      // dc=w chunk

  // K-frag read offsets (swizzled): chunk XOR with ln15&7
  const int kx  = 8 * (ln15 & 7);
  const int kc0 = (8 * lg) ^ kx;         // sd=0
  const int kc1 = (32 + 8 * lg) ^ kx;    // sd=1

#define STAGE(buf, kv0)                                                        \
  do {                                                                         \
    gld16(Kg + (size_t)((kv0) + 16 * w + krow_lo) * E3 + kcol,                 \
          &Ks[buf][1024 * w]);                                                 \
    gld16(Kg + (size_t)((kv0) + 16 * w + 8 + krow_lo) * E3 + kcol,             \
          &Ks[buf][1024 * w + 512]);                                           \
    gld16(Vg + (size_t)((kv0) + vkv) * E3 + vcol, &Vs[buf][1024 * w]);         \
    gld16(Vg + (size_t)((kv0) + 32 + vkv) * E3 + vcol,                         \
          &Vs[buf][1024 * w + 512]);                                           \
  } while (0)

  f32x4_t o[4] = {};
  float mrow = -3e38f, lrow = 0.0f;
  const int nt_tiles = qt + 1;

  STAGE(0, 0);
  int cur = 0;

  for (int kvt = 0; kvt < nt_tiles; ++kvt) {
    const int kv0 = kvt * 64;
    asm volatile("s_barrier" ::: "memory");  // all waves done reading buf[cur^1]
    if (kvt + 1 < nt_tiles) {
      STAGE(cur ^ 1, kv0 + 64);
      asm volatile("s_waitcnt vmcnt(4)" ::: "memory");
    } else {
      asm volatile("s_waitcnt vmcnt(0)" ::: "memory");
    }
    asm volatile("s_barrier" ::: "memory");  // buf[cur] ready for all waves

    // ---- issue V tr-reads early (latency hides under QK^T + softmax) ----
    // elem j of half h = V[kv0 + 32*s2 + 16*h + 4*lg + j][16*nt + ln15].
    const __attribute__((address_space(3))) u16* vp =
        (const __attribute__((address_space(3))) u16*)&Vs[cur][4 * l];
    s4v vf[4][2][2];
#pragma unroll
    for (int nt = 0; nt < 4; ++nt) {
      // OFF bytes = 2048*nt + 1024*s2 + 512*h
      if (nt == 0) { vf[0][0][0]=tr16<0>(vp);    vf[0][0][1]=tr16<512>(vp);
                     vf[0][1][0]=tr16<1024>(vp); vf[0][1][1]=tr16<1536>(vp); }
      if (nt == 1) { vf[1][0][0]=tr16<2048>(vp); vf[1][0][1]=tr16<2560>(vp);
                     vf[1][1][0]=tr16<3072>(vp); vf[1][1][1]=tr16<3584>(vp); }
      if (nt == 2) { vf[2][0][0]=tr16<4096>(vp); vf[2][0][1]=tr16<4608>(vp);
                     vf[2][1][0]=tr16<5120>(vp); vf[2][1][1]=tr16<5632>(vp); }
      if (nt == 3) { vf[3][0][0]=tr16<6144>(vp); vf[3][0][1]=tr16<6656>(vp);
                     vf[3][1][0]=tr16<7168>(vp); vf[3][1][1]=tr16<7680>(vp); }
    }

    // ---- S^T = mfma(K, Q): lane holds S[q=qrow+ln15][kv=kv0+16ks+4lg+r] ----
    f32x4_t tacc[4];
    __builtin_amdgcn_s_setprio(1);
#pragma unroll
    for (int ks = 0; ks < 4; ++ks) {
      const int R = 16 * ks + ln15;
      short8_t kf0 = *reinterpret_cast<const short8_t*>(&Ks[cur][R * 64 + kc0]);
      short8_t kf1 = *reinterpret_cast<const short8_t*>(&Ks[cur][R * 64 + kc1]);
      f32x4_t a = {0.f, 0.f, 0.f, 0.f};
      a = __builtin_amdgcn_mfma_f32_16x16x32_bf16(kf0, qf[0], a, 0, 0, 0);
      a = __builtin_amdgcn_mfma_f32_16x16x32_bf16(kf1, qf[1], a, 0, 0, 0);
      tacc[ks] = a;
    }
    __builtin_amdgcn_s_setprio(0);

    // ---- causal mask (diagonal tile only) ----
    if (kvt == qt) {
      const int qg = qrow + ln15;
#pragma unroll
      for (int ks = 0; ks < 4; ++ks)
#pragma unroll
        for (int r = 0; r < 4; ++r)
          if (kv0 + 16 * ks + 4 * lg + r > qg) tacc[ks][r] = -3e38f;
    }

    // ---- online softmax: lane owns 16 of row q=ln15's values ----
    float rm = fmaxf(
        fmaxf(fmaxf(fmaxf(tacc[0][0], tacc[0][1]), fmaxf(tacc[0][2], tacc[0][3])),
              fmaxf(fmaxf(tacc[1][0], tacc[1][1]), fmaxf(tacc[1][2], tacc[1][3]))),
        fmaxf(fmaxf(fmaxf(tacc[2][0], tacc[2][1]), fmaxf(tacc[2][2], tacc[2][3])),
              fmaxf(fmaxf(tacc[3][0], tacc[3][1]), fmaxf(tacc[3][2], tacc[3][3]))));
    rm = fmaxf(rm, __shfl_xor(rm, 16, 64));
    rm = fmaxf(rm, __shfl_xor(rm, 32, 64));

    // THR=0 exact-skip: when skipped, the rescale would have been *1.0 exactly
    if (__any(rm > mrow)) {
      const float nm = fmaxf(mrow, rm);
      const float sc = exp2f((mrow - nm) * L2E);
      mrow = nm;
      lrow *= sc;
#pragma unroll
      for (int r = 0; r < 4; ++r) {
        const float so = __shfl(sc, 20 * lg + r, 64);
#pragma unroll
        for (int nt = 0; nt < 4; ++nt) o[nt][r] *= so;
      }
    }

    const float nmL = mrow * L2E;
    float p[4][4];
    float rs = 0.0f;
#pragma unroll
    for (int ks = 0; ks < 4; ++ks)
#pragma unroll
      for (int r = 0; r < 4; ++r) {
        const float pv = exp2f(fmaf(tacc[ks][r], L2E, -nmL));
        p[ks][r] = pv;
        rs += pv;
      }
    rs += __shfl_xor(rs, 16, 64);
    rs += __shfl_xor(rs, 32, 64);
    lrow += rs;

    // ---- P pack: 8x v_cvt_pk_bf16_f32 (shorts[0..3]=p[2s2], [4..7]=p[2s2+1]) ----
    short8_t pf[2];
#pragma unroll
    for (int s2 = 0; s2 < 2; ++s2) {
      u32x4_t pu;
      pu[0] = pkbf(p[2 * s2][0], p[2 * s2][1]);
      pu[1] = pkbf(p[2 * s2][2], p[2 * s2][3]);
      pu[2] = pkbf(p[2 * s2 + 1][0], p[2 * s2 + 1][1]);
      pu[3] = pkbf(p[2 * s2 + 1][2], p[2 * s2 + 1][3]);
      pf[s2] = __builtin_bit_cast(short8_t, pu);
    }

    asm volatile("s_waitcnt lgkmcnt(0)");
    __builtin_amdgcn_sched_barrier(0);

    __builtin_amdgcn_s_setprio(1);
#pragma unroll
    for (int nt = 0; nt < 4; ++nt) {
#pragma unroll
      for (int s2 = 0; s2 < 2; ++s2) {
        short8_t bv = __builtin_shufflevector(vf[nt][s2][0], vf[nt][s2][1],
                                              0, 1, 2, 3, 4, 5, 6, 7);
        o[nt] = __builtin_amdgcn_mfma_f32_16x16x32_bf16(pf[s2], bv, o[nt], 0, 0, 0);
      }
    }
    __builtin_amdgcn_s_setprio(0);
    cur ^= 1;
  }
#undef STAGE

  // ---- epilogue: normalize and write ctx ----
  const float linv = 1.0f / lrow;
#pragma unroll
  for (int r = 0; r < 4; ++r) {
    const float li = __shfl(linv, 20 * lg + r, 64);
    u16* op = ctx + (size_t)(b * S_LEN + qrow + 4 * lg + r) * EMB + h * HD;
#pragma unroll
    for (int nt = 0; nt < 4; ++nt)
      op[nt * 16 + ln15] = f2bf(o[nt][r] * li);
  }
}

// ---------------------------------------------------------------------------
extern "C" void kernel_launch(void* const* d_in, const int* in_sizes, int n_in,
                              void* d_out, int out_size, void* d_ws, size_t ws_size,
                              hipStream_t stream) {
  const float* x  = (const float*)d_in[0];
  const float* Wq = (const float*)d_in[1];
  const float* Wk = (const float*)d_in[2];
  const float* Wv = (const float*)d_in[3];
  const float* Wo = (const float*)d_in[4];
  const float* bo = (const float*)d_in[5];

  u16* ws   = (u16*)d_ws;
  u16* xb   = ws;                               // 4096*1024
  u16* wcat = xb + (size_t)MR * EMB;            // 3*1024*1024 (Wq|Wk|Wv rows)
  u16* wob  = wcat + (size_t)3 * EMB * EMB;     // 1024*1024
  u16* qkv  = wob + (size_t)EMB * EMB;          // 4096*3072
  u16* ctxb = qkv + (size_t)MR * E3;            // 4096*1024

  // fused fp32 -> bf16 (x | Wq*0.125 | Wk | Wv | Wo), dest contiguous at xb
  k_cvt_all<<<8192, 256, 0, stream>>>(x, Wq, Wk, Wv, Wo, xb);

  // QKV = x @ Wcat^T  (M=4096, N=3072, K=1024), bf16 out
  k_gemm_bt<false><<<dim3(E3 / 128, MR / 128), 256, 0, stream>>>(
      xb, wcat, qkv, nullptr, MR, E3, EMB);

  // causal flash attention -> ctx (bf16)
  k_attn2<<<dim3(BATCH * NH, 32), 256, 0, stream>>>(qkv, ctxb);

  // out = ctx @ Wo^T + bo  (fp32 out)
  k_gemm_bt<true><<<dim3(EMB / 128, MR / 128), 256, 0, stream>>>(
      ctxb, wob, d_out, bo, MR, EMB, EMB);
}

// Round 9
// 117.593 us; speedup vs baseline: 1.2888x; 1.0553x over previous
//
#include <hip/hip_runtime.h>
#include <hip/hip_bf16.h>

typedef __attribute__((ext_vector_type(8))) short short8_t;
typedef __attribute__((ext_vector_type(4))) short s4v;
typedef __attribute__((ext_vector_type(4))) float f32x4_t;
typedef __attribute__((ext_vector_type(4))) unsigned u32x4_t;
using u16 = unsigned short;

constexpr int S_LEN = 2048;
constexpr int EMB   = 1024;
constexpr int NH    = 16;
constexpr int HD    = 64;
constexpr int BATCH = 2;
constexpr int MR    = BATCH * S_LEN;  // 4096
constexpr int E3    = 3 * EMB;        // 3072

#define L2E 1.44269504f

__device__ __forceinline__ u16 f2bf(float f) {
  unsigned u = __builtin_bit_cast(unsigned, f);
  unsigned r = 0x7fffu + ((u >> 16) & 1u);
  return (u16)((u + r) >> 16);
}

// packed f32x2 -> bf16x2 via intrinsic (RNE, compiler emits v_cvt_pk_bf16_f32)
__device__ __forceinline__ unsigned pkbf(float a, float b) {
  __hip_bfloat162 h = __float22bfloat162_rn(make_float2(a, b));
  unsigned u;
  __builtin_memcpy(&u, &h, 4);
  return u;
}

__device__ __forceinline__ void gld16(const void* g, void* l) {
  __builtin_amdgcn_global_load_lds(
      (const __attribute__((address_space(1))) void*)g,
      (__attribute__((address_space(3))) void*)l, 16, 0, 0);
}

// hardware transpose read. Canonical per-lane address = base + 8B*lane:
// lane l, elem j <- lds_elem[64*(l>>4) + 16*j + (l&15)] (+ offset/2 elems).
template <int OFF>
__device__ __forceinline__ s4v tr16(const __attribute__((address_space(3))) u16* p) {
  s4v d;
  asm volatile("ds_read_b64_tr_b16 %0, %1 offset:%2"
               : "=v"(d) : "v"(p), "n"(OFF));
  return d;
}

// ---------------- fused fp32 -> bf16 conversion ----------------------------
// dest layout (contiguous in ws): xb(4M) | Wq(1M,*0.125) | Wk | Wv | Wo
__global__ void k_cvt_all(const float* __restrict__ x, const float* __restrict__ Wq,
                          const float* __restrict__ Wk, const float* __restrict__ Wv,
                          const float* __restrict__ Wo, u16* __restrict__ out) {
  int i = blockIdx.x * 256 + threadIdx.x;  // float4 index, total 2M
  const float* src;
  int j;
  float sc = 1.0f;
  if (i < (1 << 20)) {
    src = x; j = i;
  } else {
    int jj = i - (1 << 20);
    int r = jj >> 18;
    j = jj & ((1 << 18) - 1);
    src = (r == 0) ? Wq : (r == 1) ? Wk : (r == 2) ? Wv : Wo;
    if (r == 0) sc = 0.125f;  // fold softmax 1/sqrt(64)
  }
  float4 v = reinterpret_cast<const float4*>(src)[j];
  ushort4 o;
  o.x = f2bf(v.x * sc); o.y = f2bf(v.y * sc);
  o.z = f2bf(v.z * sc); o.w = f2bf(v.w * sc);
  reinterpret_cast<ushort4*>(out)[i] = o;
}

// ---------------- bf16 GEMM, B^T input (C = A @ B^T), 128x128 tile ---------
// 2-phase double-buffered staging (attn-verified barrier/vmcnt protocol):
// per iter: barrier; STAGE(next)->buf^1; vmcnt(4) [current tile landed];
// barrier; ds_read+MFMA from buf. T1 XCD swizzle (grids % 8 == 0).
template <bool F32OUT>
__global__ __launch_bounds__(256) void k_gemm_bt(
    const u16* __restrict__ A, const u16* __restrict__ Bw,
    void* __restrict__ Cv, const float* __restrict__ bias,
    int M, int N, int K) {
  __shared__ short As[2][128 * 32];
  __shared__ short Bs[2][128 * 32];
  const int t    = threadIdx.x;
  const int w    = t >> 6;
  const int ln15 = t & 15;
  const int lg   = (t >> 4) & 3;
  const int wr   = w >> 1, wc = w & 1;

  // XCD-aware block remap (nwg % 8 == 0 for all launches here)
  const int nwgx = gridDim.x;
  const int lin  = blockIdx.y * nwgx + blockIdx.x;
  const int cpx  = (nwgx * gridDim.y) >> 3;
  const int lin2 = (lin & 7) * cpx + (lin >> 3);
  const int m0   = (lin2 / nwgx) * 128;
  const int n0   = (lin2 % nwgx) * 128;

  const int srow = t >> 2;
  const int scol = (t & 3) * 8;
  const u16* gA = A + (size_t)(m0 + srow) * K + scol;
  const u16* gB = Bw + (size_t)(n0 + srow) * K + scol;
  const int lofs = w * 512;  // wave-uniform LDS base (lane adds 16B slot)

  f32x4_t acc[4][4] = {};

#define GSTAGE(buf, k0)                                                        \
  do {                                                                         \
    gld16(gA + (k0), &As[buf][lofs]);                                          \
    gld16(gA + (size_t)64 * K + (k0), &As[buf][lofs + 2048]);                  \
    gld16(gB + (k0), &Bs[buf][lofs]);                                          \
    gld16(gB + (size_t)64 * K + (k0), &Bs[buf][lofs + 2048]);                  \
  } while (0)

  const int nk = K >> 5;
  GSTAGE(0, 0);
  int cur = 0;

  for (int ki = 0; ki < nk; ++ki) {
    asm volatile("s_barrier" ::: "memory");  // all waves done reading buf^1
    if (ki + 1 < nk) {
      GSTAGE(cur ^ 1, (ki + 1) * 32);
      asm volatile("s_waitcnt vmcnt(4)" ::: "memory");  // tile ki landed
    } else {
      asm volatile("s_waitcnt vmcnt(0)" ::: "memory");
    }
    asm volatile("s_barrier" ::: "memory");  // buf[cur] ready for all waves

    short8_t af[4], bf[4];
#pragma unroll
    for (int i = 0; i < 4; ++i) {
      af[i] = *reinterpret_cast<const short8_t*>(
          &As[cur][(wr * 64 + i * 16 + ln15) * 32 + 8 * lg]);
      bf[i] = *reinterpret_cast<const short8_t*>(
          &Bs[cur][(wc * 64 + i * 16 + ln15) * 32 + 8 * lg]);
    }
#pragma unroll
    for (int i = 0; i < 4; ++i)
#pragma unroll
      for (int j = 0; j < 4; ++j)
        acc[i][j] = __builtin_amdgcn_mfma_f32_16x16x32_bf16(
            af[i], bf[j], acc[i][j], 0, 0, 0);
    cur ^= 1;
  }
#undef GSTAGE

  if (F32OUT) {
    float* C = reinterpret_cast<float*>(Cv);
#pragma unroll
    for (int i = 0; i < 4; ++i)
#pragma unroll
      for (int j = 0; j < 4; ++j) {
        const int col = n0 + wc * 64 + j * 16 + ln15;
        const float bv = bias ? bias[col] : 0.0f;
#pragma unroll
        for (int r = 0; r < 4; ++r) {
          const int row = m0 + wr * 64 + i * 16 + lg * 4 + r;
          C[(size_t)row * N + col] = acc[i][j][r] + bv;
        }
      }
  } else {
    u16* C = reinterpret_cast<u16*>(Cv);
#pragma unroll
    for (int i = 0; i < 4; ++i)
#pragma unroll
      for (int j = 0; j < 4; ++j) {
        const int col = n0 + wc * 64 + j * 16 + ln15;
#pragma unroll
        for (int r = 0; r < 4; ++r) {
          const int row = m0 + wr * 64 + i * 16 + lg * 4 + r;
          C[(size_t)row * N + col] = f2bf(acc[i][j][r]);
        }
      }
  }
}

// ---------------- causal flash attention, swapped-QK^T ----------------------
// r8-verified: 51.4 us. 4 waves/block, 16 q-rows/wave, KV tiles 64, frozen.
__global__ __launch_bounds__(256, 4) void k_attn2(const u16* __restrict__ QKV,
                                                  u16* __restrict__ ctx) {
  __shared__ u16 Ks[2][64 * 64];
  __shared__ u16 Vs[2][64 * 64];

  const int t    = threadIdx.x;
  const int w    = t >> 6;
  const int l    = t & 63;
  const int ln15 = t & 15;
  const int lg   = (l >> 4) & 3;

  // LPT: heaviest qt dispatched first
  const int qt = 31 - blockIdx.y;
  const int bh = blockIdx.x;
  const int b  = bh >> 4, h = bh & 15;

  const u16* KVb = QKV + (size_t)b * S_LEN * E3 + h * HD;
  const u16* Kg  = KVb + 1024;
  const u16* Vg  = KVb + 2048;
  const int qrow = qt * 64 + w * 16;

  // Q fragments (B-operand): lane (ln15,lg): Q[qrow+ln15][32*sd + 8*lg ..+7]
  short8_t qf[2];
  {
    const u16* qp = KVb + (size_t)(qrow + ln15) * E3 + 8 * lg;
    qf[0] = *reinterpret_cast<const short8_t*>(qp);
    qf[1] = *reinterpret_cast<const short8_t*>(qp + 32);
  }

  // staging address components
  const int krow_lo = l >> 3;                    // row&7 of K stage row
  const int kcol    = 8 * ((l & 7) ^ krow_lo);   // pre-swizzled source col
  const int vkv     = l >> 1;                    // 0..31
  const int vcol    = 16 * w + 8 * (l & 1);      // dc=w chunk

  // K-frag read offsets (swizzled): chunk XOR with ln15&7
  const int kx  = 8 * (ln15 & 7);
  const int kc0 = (8 * lg) ^ kx;         // sd=0
  const int kc1 = (32 + 8 * lg) ^ kx;    // sd=1

#define STAGE(buf, kv0)                                                        \
  do {                                                                         \
    gld16(Kg + (size_t)((kv0) + 16 * w + krow_lo) * E3 + kcol,                 \
          &Ks[buf][1024 * w]);                                                 \
    gld16(Kg + (size_t)((kv0) + 16 * w + 8 + krow_lo) * E3 + kcol,             \
          &Ks[buf][1024 * w + 512]);                                           \
    gld16(Vg + (size_t)((kv0) + vkv) * E3 + vcol, &Vs[buf][1024 * w]);         \
    gld16(Vg + (size_t)((kv0) + 32 + vkv) * E3 + vcol,                         \
          &Vs[buf][1024 * w + 512]);                                           \
  } while (0)

  f32x4_t o[4] = {};
  float mrow = -3e38f, lrow = 0.0f;
  const int nt_tiles = qt + 1;

  STAGE(0, 0);
  int cur = 0;

  for (int kvt = 0; kvt < nt_tiles; ++kvt) {
    const int kv0 = kvt * 64;
    asm volatile("s_barrier" ::: "memory");  // all waves done reading buf[cur^1]
    if (kvt + 1 < nt_tiles) {
      STAGE(cur ^ 1, kv0 + 64);
      asm volatile("s_waitcnt vmcnt(4)" ::: "memory");
    } else {
      asm volatile("s_waitcnt vmcnt(0)" ::: "memory");
    }
    asm volatile("s_barrier" ::: "memory");  // buf[cur] ready for all waves

    // ---- issue V tr-reads early (latency hides under QK^T + softmax) ----
    // elem j of half h = V[kv0 + 32*s2 + 16*h + 4*lg + j][16*nt + ln15].
    const __attribute__((address_space(3))) u16* vp =
        (const __attribute__((address_space(3))) u16*)&Vs[cur][4 * l];
    s4v vf[4][2][2];
#pragma unroll
    for (int nt = 0; nt < 4; ++nt) {
      // OFF bytes = 2048*nt + 1024*s2 + 512*h
      if (nt == 0) { vf[0][0][0]=tr16<0>(vp);    vf[0][0][1]=tr16<512>(vp);
                     vf[0][1][0]=tr16<1024>(vp); vf[0][1][1]=tr16<1536>(vp); }
      if (nt == 1) { vf[1][0][0]=tr16<2048>(vp); vf[1][0][1]=tr16<2560>(vp);
                     vf[1][1][0]=tr16<3072>(vp); vf[1][1][1]=tr16<3584>(vp); }
      if (nt == 2) { vf[2][0][0]=tr16<4096>(vp); vf[2][0][1]=tr16<4608>(vp);
                     vf[2][1][0]=tr16<5120>(vp); vf[2][1][1]=tr16<5632>(vp); }
      if (nt == 3) { vf[3][0][0]=tr16<6144>(vp); vf[3][0][1]=tr16<6656>(vp);
                     vf[3][1][0]=tr16<7168>(vp); vf[3][1][1]=tr16<7680>(vp); }
    }

    // ---- S^T = mfma(K, Q): lane holds S[q=qrow+ln15][kv=kv0+16ks+4lg+r] ----
    f32x4_t tacc[4];
    __builtin_amdgcn_s_setprio(1);
#pragma unroll
    for (int ks = 0; ks < 4; ++ks) {
      const int R = 16 * ks + ln15;
      short8_t kf0 = *reinterpret_cast<const short8_t*>(&Ks[cur][R * 64 + kc0]);
      short8_t kf1 = *reinterpret_cast<const short8_t*>(&Ks[cur][R * 64 + kc1]);
      f32x4_t a = {0.f, 0.f, 0.f, 0.f};
      a = __builtin_amdgcn_mfma_f32_16x16x32_bf16(kf0, qf[0], a, 0, 0, 0);
      a = __builtin_amdgcn_mfma_f32_16x16x32_bf16(kf1, qf[1], a, 0, 0, 0);
      tacc[ks] = a;
    }
    __builtin_amdgcn_s_setprio(0);

    // ---- causal mask (diagonal tile only) ----
    if (kvt == qt) {
      const int qg = qrow + ln15;
#pragma unroll
      for (int ks = 0; ks < 4; ++ks)
#pragma unroll
        for (int r = 0; r < 4; ++r)
          if (kv0 + 16 * ks + 4 * lg + r > qg) tacc[ks][r] = -3e38f;
    }

    // ---- online softmax: lane owns 16 of row q=ln15's values ----
    float rm = fmaxf(
        fmaxf(fmaxf(fmaxf(tacc[0][0], tacc[0][1]), fmaxf(tacc[0][2], tacc[0][3])),
              fmaxf(fmaxf(tacc[1][0], tacc[1][1]), fmaxf(tacc[1][2], tacc[1][3]))),
        fmaxf(fmaxf(fmaxf(tacc[2][0], tacc[2][1]), fmaxf(tacc[2][2], tacc[2][3])),
              fmaxf(fmaxf(tacc[3][0], tacc[3][1]), fmaxf(tacc[3][2], tacc[3][3]))));
    rm = fmaxf(rm, __shfl_xor(rm, 16, 64));
    rm = fmaxf(rm, __shfl_xor(rm, 32, 64));

    // THR=0 exact-skip: when skipped, the rescale would have been *1.0 exactly
    if (__any(rm > mrow)) {
      const float nm = fmaxf(mrow, rm);
      const float sc = exp2f((mrow - nm) * L2E);
      mrow = nm;
      lrow *= sc;
#pragma unroll
      for (int r = 0; r < 4; ++r) {
        const float so = __shfl(sc, 20 * lg + r, 64);
#pragma unroll
        for (int nt = 0; nt < 4; ++nt) o[nt][r] *= so;
      }
    }

    const float nmL = mrow * L2E;
    float p[4][4];
    float rs = 0.0f;
#pragma unroll
    for (int ks = 0; ks < 4; ++ks)
#pragma unroll
      for (int r = 0; r < 4; ++r) {
        const float pv = exp2f(fmaf(tacc[ks][r], L2E, -nmL));
        p[ks][r] = pv;
        rs += pv;
      }
    rs += __shfl_xor(rs, 16, 64);
    rs += __shfl_xor(rs, 32, 64);
    lrow += rs;

    // ---- P pack: 8x v_cvt_pk_bf16_f32 (shorts[0..3]=p[2s2], [4..7]=p[2s2+1]) ----
    short8_t pf[2];
#pragma unroll
    for (int s2 = 0; s2 < 2; ++s2) {
      u32x4_t pu;
      pu[0] = pkbf(p[2 * s2][0], p[2 * s2][1]);
      pu[1] = pkbf(p[2 * s2][2], p[2 * s2][3]);
      pu[2] = pkbf(p[2 * s2 + 1][0], p[2 * s2 + 1][1]);
      pu[3] = pkbf(p[2 * s2 + 1][2], p[2 * s2 + 1][3]);
      pf[s2] = __builtin_bit_cast(short8_t, pu);
    }

    asm volatile("s_waitcnt lgkmcnt(0)");
    __builtin_amdgcn_sched_barrier(0);

    __builtin_amdgcn_s_setprio(1);
#pragma unroll
    for (int nt = 0; nt < 4; ++nt) {
#pragma unroll
      for (int s2 = 0; s2 < 2; ++s2) {
        short8_t bv = __builtin_shufflevector(vf[nt][s2][0], vf[nt][s2][1],
                                              0, 1, 2, 3, 4, 5, 6, 7);
        o[nt] = __builtin_amdgcn_mfma_f32_16x16x32_bf16(pf[s2], bv, o[nt], 0, 0, 0);
      }
    }
    __builtin_amdgcn_s_setprio(0);
    cur ^= 1;
  }
#undef STAGE

  // ---- epilogue: normalize and write ctx ----
  const float linv = 1.0f / lrow;
#pragma unroll
  for (int r = 0; r < 4; ++r) {
    const float li = __shfl(linv, 20 * lg + r, 64);
    u16* op = ctx + (size_t)(b * S_LEN + qrow + 4 * lg + r) * EMB + h * HD;
#pragma unroll
    for (int nt = 0; nt < 4; ++nt)
      op[nt * 16 + ln15] = f2bf(o[nt][r] * li);
  }
}

// ---------------------------------------------------------------------------
extern "C" void kernel_launch(void* const* d_in, const int* in_sizes, int n_in,
                              void* d_out, int out_size, void* d_ws, size_t ws_size,
                              hipStream_t stream) {
  const float* x  = (const float*)d_in[0];
  const float* Wq = (const float*)d_in[1];
  const float* Wk = (const float*)d_in[2];
  const float* Wv = (const float*)d_in[3];
  const float* Wo = (const float*)d_in[4];
  const float* bo = (const float*)d_in[5];

  u16* ws   = (u16*)d_ws;
  u16* xb   = ws;                               // 4096*1024
  u16* wcat = xb + (size_t)MR * EMB;            // 3*1024*1024 (Wq|Wk|Wv rows)
  u16* wob  = wcat + (size_t)3 * EMB * EMB;     // 1024*1024
  u16* qkv  = wob + (size_t)EMB * EMB;          // 4096*3072
  u16* ctxb = qkv + (size_t)MR * E3;            // 4096*1024

  // fused fp32 -> bf16 (x | Wq*0.125 | Wk | Wv | Wo), dest contiguous at xb
  k_cvt_all<<<8192, 256, 0, stream>>>(x, Wq, Wk, Wv, Wo, xb);

  // QKV = x @ Wcat^T  (M=4096, N=3072, K=1024), bf16 out
  k_gemm_bt<false><<<dim3(E3 / 128, MR / 128), 256, 0, stream>>>(
      xb, wcat, qkv, nullptr, MR, E3, EMB);

  // causal flash attention -> ctx (bf16)
  k_attn2<<<dim3(BATCH * NH, 32), 256, 0, stream>>>(qkv, ctxb);

  // out = ctx @ Wo^T + bo  (fp32 out)
  k_gemm_bt<true><<<dim3(EMB / 128, MR / 128), 256, 0, stream>>>(
      ctxb, wob, d_out, bo, MR, EMB, EMB);
}